// Round 2
// baseline (1137.704 us; speedup 1.0000x reference)
//
#include <hip/hip_runtime.h>

// BetaBernoulliMixture: per row r, per time t:
//   s_prev = #ones in obs[r, 0..t-1];  f_prev = t - s_prev
//   a1 = alpha1+s_prev, b1 = beta1+f_prev, a2 = alpha2+s_prev, b2 = beta2+f_prev
//   d(t) = clog2 - clog1 = sum_{u<t} [ log(sel2_u*(AB1+u)) - log(sel1_u*(AB2+u)) ]
//   post_mixweight = w / (w + (1-w)*exp(d))
// Output layout: [5, B, T] = {a1, b1, a2, b2, post_mixweight}
//
// Structure: 1 block/row, 256 threads, VEC=8 contiguous elems/thread/segment
// -> 4 segments of 2048 elems; per segment: thread-local serial prefix +
// one wave shuffle-scan over thread totals + LDS cross-wave combine (x2:
// bits then deltas), vectorized float4 IO, nontemporal stores (write-once).

#define BLOCK 256
#define VEC 8

typedef float v4f __attribute__((ext_vector_type(4)));

__global__ __launch_bounds__(BLOCK) void bbm_kernel(
    const float* __restrict__ obs,
    const float* __restrict__ alpha1, const float* __restrict__ beta1,
    const float* __restrict__ alpha2, const float* __restrict__ beta2,
    const float* __restrict__ mixw,
    float* __restrict__ out,
    int T, size_t bt)
{
    const int row  = blockIdx.x;
    const int tid  = threadIdx.x;
    const int lane = tid & 63;
    const int wid  = tid >> 6;

    __shared__ int   sPart[4];
    __shared__ float dPart[4];

    const float A1 = alpha1[row], B1 = beta1[row];
    const float A2 = alpha2[row], B2 = beta2[row];
    const float w  = mixw[0];
    const float AB1 = A1 + B1, AB2 = A2 + B2;
    const float w2 = 1.0f - w;

    const float* __restrict__ orow = obs + (size_t)row * T;
    float* __restrict__ obase = out + (size_t)row * T;

    int   carry_s = 0;
    float carry_d = 0.0f;

    const int EPB  = BLOCK * VEC;       // 2048
    const int segs = T / EPB;           // 4 for T=8192

    for (int seg = 0; seg < segs; ++seg) {
        const int t0 = seg * EPB + tid * VEC;

        // ---- vector load 8 contiguous obs ----
        v4f o0 = *(const v4f*)(orow + t0);
        v4f o1 = *(const v4f*)(orow + t0 + 4);
        float ov[VEC] = {o0.x, o0.y, o0.z, o0.w, o1.x, o1.y, o1.z, o1.w};

        // ---- thread-local exclusive bit prefix ----
        int bit[VEC], sloc[VEC];
        int ts = 0;
        #pragma unroll
        for (int j = 0; j < VEC; ++j) { bit[j] = ov[j] > 0.5f; sloc[j] = ts; ts += bit[j]; }

        // ---- wave scan over thread totals + LDS combine ----
        int incl = ts;
        #pragma unroll
        for (int off = 1; off < 64; off <<= 1) {
            int n = __shfl_up(incl, off, 64);
            if (lane >= off) incl += n;
        }
        if (lane == 63) sPart[wid] = incl;
        __syncthreads();
        int prior = 0, total = 0;
        #pragma unroll
        for (int wI = 0; wI < 4; ++wI) {
            int p = sPart[wI];
            total += p;
            if (wI < wid) prior += p;
        }
        const int tbase_s = carry_s + prior + (incl - ts);

        // ---- per-elem delta + thread-local exclusive prefix ----
        float dloc[VEC];
        float td = 0.0f;
        #pragma unroll
        for (int j = 0; j < VEC; ++j) {
            const float ft = (float)(t0 + j);
            const float fs = (float)(tbase_s + sloc[j]);
            const float fp = ft - fs;
            const float sel1 = bit[j] ? (A1 + fs) : (B1 + fp);
            const float sel2 = bit[j] ? (A2 + fs) : (B2 + fp);
            const float delta = __logf(sel2 * (AB1 + ft)) - __logf(sel1 * (AB2 + ft));
            dloc[j] = td;
            td += delta;
        }

        // ---- wave scan over thread delta totals + LDS combine ----
        float incl_d = td;
        #pragma unroll
        for (int off = 1; off < 64; off <<= 1) {
            float n = __shfl_up(incl_d, off, 64);
            if (lane >= off) incl_d += n;
        }
        if (lane == 63) dPart[wid] = incl_d;
        __syncthreads();
        float priord = 0.0f, totald = 0.0f;
        #pragma unroll
        for (int wI = 0; wI < 4; ++wI) {
            float p = dPart[wI];
            totald += p;
            if (wI < wid) priord += p;
        }
        const float tbase_d = carry_d + priord + (incl_d - td);

        // ---- outputs: 2 x float4 per stream, nontemporal ----
        #pragma unroll
        for (int h = 0; h < VEC / 4; ++h) {
            v4f va1, vb1, va2, vb2, vpm;
            #pragma unroll
            for (int j = 0; j < 4; ++j) {
                const int e  = h * 4 + j;
                const float ft = (float)(t0 + e);
                const float fs = (float)(tbase_s + sloc[e]);
                const float fp = ft - fs;
                const float d  = tbase_d + dloc[e];
                const float pm = w / (w + w2 * __expf(d));
                va1[j] = A1 + fs;
                vb1[j] = B1 + fp;
                va2[j] = A2 + fs;
                vb2[j] = B2 + fp;
                vpm[j] = pm;
            }
            float* p = obase + t0 + h * 4;
            __builtin_nontemporal_store(va1, (v4f*)(p));
            __builtin_nontemporal_store(vb1, (v4f*)(p + bt));
            __builtin_nontemporal_store(va2, (v4f*)(p + 2 * bt));
            __builtin_nontemporal_store(vb2, (v4f*)(p + 3 * bt));
            __builtin_nontemporal_store(vpm, (v4f*)(p + 4 * bt));
        }

        carry_s += total;
        carry_d += totald;
    }
}

extern "C" void kernel_launch(void* const* d_in, const int* in_sizes, int n_in,
                              void* d_out, int out_size, void* d_ws, size_t ws_size,
                              hipStream_t stream) {
    const float* obs    = (const float*)d_in[0];
    const float* alpha1 = (const float*)d_in[1];
    const float* beta1  = (const float*)d_in[2];
    const float* alpha2 = (const float*)d_in[3];
    const float* beta2  = (const float*)d_in[4];
    const float* mixw   = (const float*)d_in[5];

    const int Bn = in_sizes[1];
    const int Tn = in_sizes[0] / Bn;
    const size_t bt = (size_t)Bn * (size_t)Tn;

    bbm_kernel<<<Bn, BLOCK, 0, stream>>>(obs, alpha1, beta1, alpha2, beta2,
                                         mixw, (float*)d_out, Tn, bt);
}

// Round 3
// 760.392 us; speedup vs baseline: 1.4962x; 1.4962x over previous
//
#include <hip/hip_runtime.h>

// BetaBernoulliMixture: per row r, per time t:
//   s_prev = #ones in obs[r, 0..t-1];  f_prev = t - s_prev
//   a1 = alpha1+s_prev, b1 = beta1+f_prev, a2 = alpha2+s_prev, b2 = beta2+f_prev
//   d(t) = sum_{u<t} [ log(sel2_u*(AB1+u)) - log(sel1_u*(AB2+u)) ]
//   post_mixweight = w / (w + (1-w)*exp(d))
// Output layout: [5, B, T] = {a1, b1, a2, b2, post_mixweight}
//
// R3 structure: 1 block/row, 256 threads, VEC=4 lane-contiguous elems/thread
// -> 8 segments of 1024. Bit cumsum via __ballot+popc (short dep chain);
// delta cumsum via wave shuffle-scan + LDS combine. All loads/stores are
// float4 with lane-contiguous addressing -> full 32B sectors for NT stores
// (R2's 2x write amplification came from 32B-strided NT float4 stores).

#define BLOCK 256
#define VEC 4

typedef float v4f __attribute__((ext_vector_type(4)));

__global__ __launch_bounds__(BLOCK) void bbm_kernel(
    const float* __restrict__ obs,
    const float* __restrict__ alpha1, const float* __restrict__ beta1,
    const float* __restrict__ alpha2, const float* __restrict__ beta2,
    const float* __restrict__ mixw,
    float* __restrict__ out,
    int T, size_t bt)
{
    const int row  = blockIdx.x;
    const int tid  = threadIdx.x;
    const int lane = tid & 63;
    const int wid  = tid >> 6;

    __shared__ int   sPart[4];
    __shared__ float dPart[4];

    const float A1 = alpha1[row], B1 = beta1[row];
    const float A2 = alpha2[row], B2 = beta2[row];
    const float w  = mixw[0];
    const float AB1 = A1 + B1, AB2 = A2 + B2;
    const float w2 = 1.0f - w;

    const float* __restrict__ orow = obs + (size_t)row * T;
    float* __restrict__ obase = out + (size_t)row * T;

    const unsigned long long lt_mask = ((unsigned long long)1 << lane) - 1;

    int   carry_s = 0;
    float carry_d = 0.0f;

    const int EPB  = BLOCK * VEC;       // 1024
    const int segs = T / EPB;           // 8 for T=8192

    // preload first segment
    v4f cur = *(const v4f*)(orow + tid * VEC);

    for (int seg = 0; seg < segs; ++seg) {
        const int t0 = seg * EPB + tid * VEC;

        // prefetch next segment's obs before the scan chains
        v4f nxt;
        if (seg + 1 < segs) nxt = *(const v4f*)(orow + (seg + 1) * EPB + tid * VEC);

        // ---- bits + thread-local exclusive prefix ----
        int bit[VEC], sloc[VEC];
        int ts = 0;
        #pragma unroll
        for (int j = 0; j < VEC; ++j) { bit[j] = cur[j] > 0.5f; sloc[j] = ts; ts += bit[j]; }

        // ---- wave bit scan via ballot+popc (short dependency chain) ----
        unsigned long long m0 = __ballot(bit[0]);
        unsigned long long m1 = __ballot(bit[1]);
        unsigned long long m2 = __ballot(bit[2]);
        unsigned long long m3 = __ballot(bit[3]);
        const int wave_excl = __builtin_popcountll(m0 & lt_mask)
                            + __builtin_popcountll(m1 & lt_mask)
                            + __builtin_popcountll(m2 & lt_mask)
                            + __builtin_popcountll(m3 & lt_mask);
        const int wave_tot  = __builtin_popcountll(m0) + __builtin_popcountll(m1)
                            + __builtin_popcountll(m2) + __builtin_popcountll(m3);
        if (lane == 0) sPart[wid] = wave_tot;
        __syncthreads();
        int prior = 0, total = 0;
        #pragma unroll
        for (int wI = 0; wI < 4; ++wI) {
            int p = sPart[wI];
            total += p;
            if (wI < wid) prior += p;
        }
        const int tbase_s = carry_s + prior + wave_excl;

        // ---- per-elem delta + thread-local exclusive prefix ----
        float dloc[VEC];
        float td = 0.0f;
        #pragma unroll
        for (int j = 0; j < VEC; ++j) {
            const float ft = (float)(t0 + j);
            const float fs = (float)(tbase_s + sloc[j]);
            const float fp = ft - fs;
            const float sel1 = bit[j] ? (A1 + fs) : (B1 + fp);
            const float sel2 = bit[j] ? (A2 + fs) : (B2 + fp);
            const float delta = __logf(sel2 * (AB1 + ft)) - __logf(sel1 * (AB2 + ft));
            dloc[j] = td;
            td += delta;
        }

        // ---- wave shuffle-scan over thread delta totals + LDS combine ----
        float incl_d = td;
        #pragma unroll
        for (int off = 1; off < 64; off <<= 1) {
            float n = __shfl_up(incl_d, off, 64);
            if (lane >= off) incl_d += n;
        }
        if (lane == 63) dPart[wid] = incl_d;
        __syncthreads();
        float priord = 0.0f, totald = 0.0f;
        #pragma unroll
        for (int wI = 0; wI < 4; ++wI) {
            float p = dPart[wI];
            totald += p;
            if (wI < wid) priord += p;
        }
        const float tbase_d = carry_d + priord + (incl_d - td);

        // ---- outputs: one lane-contiguous float4 NT store per stream ----
        v4f va1, vb1, va2, vb2, vpm;
        #pragma unroll
        for (int j = 0; j < VEC; ++j) {
            const float ft = (float)(t0 + j);
            const float fs = (float)(tbase_s + sloc[j]);
            const float fp = ft - fs;
            const float d  = tbase_d + dloc[j];
            va1[j] = A1 + fs;
            vb1[j] = B1 + fp;
            va2[j] = A2 + fs;
            vb2[j] = B2 + fp;
            vpm[j] = w / (w + w2 * __expf(d));
        }
        float* p = obase + t0;
        __builtin_nontemporal_store(va1, (v4f*)(p));
        __builtin_nontemporal_store(vb1, (v4f*)(p + bt));
        __builtin_nontemporal_store(va2, (v4f*)(p + 2 * bt));
        __builtin_nontemporal_store(vb2, (v4f*)(p + 3 * bt));
        __builtin_nontemporal_store(vpm, (v4f*)(p + 4 * bt));

        carry_s += total;
        carry_d += totald;
        cur = nxt;
    }
}

extern "C" void kernel_launch(void* const* d_in, const int* in_sizes, int n_in,
                              void* d_out, int out_size, void* d_ws, size_t ws_size,
                              hipStream_t stream) {
    const float* obs    = (const float*)d_in[0];
    const float* alpha1 = (const float*)d_in[1];
    const float* beta1  = (const float*)d_in[2];
    const float* alpha2 = (const float*)d_in[3];
    const float* beta2  = (const float*)d_in[4];
    const float* mixw   = (const float*)d_in[5];

    const int Bn = in_sizes[1];
    const int Tn = in_sizes[0] / Bn;
    const size_t bt = (size_t)Bn * (size_t)Tn;

    bbm_kernel<<<Bn, BLOCK, 0, stream>>>(obs, alpha1, beta1, alpha2, beta2,
                                         mixw, (float*)d_out, Tn, bt);
}